// Round 10
// baseline (610.961 us; speedup 1.0000x reference)
//
#include <hip/hip_runtime.h>

typedef __attribute__((ext_vector_type(8))) short short8;
typedef __attribute__((ext_vector_type(4))) float f32x4;
typedef unsigned short ushort_t;
typedef unsigned int uint_t;

// ---------------- workspace layout (float offsets) ----------------
#define OFF_W1R   0
#define OFF_BD2F  288
#define OFF_BD1F  18720
#define OFF_EWT   (18720+73728)         // 92448
#define OFF_CT    (92448+147456)        // 239904
#define OFF_CC    (239904+131072)       // 370976
#define OFF_DWT   (370976+1024)         // 372000
#define OFF_D1R   (372000+147456)       // 519456 (unused)
#define OFF_D3R   (593184+18432)        // 611616
#define WS_WEIGHTS (611616+288)         // 611904
#define OFF_W2BF  WS_WEIGHTS
#define OFF_W3BF  (OFF_W2BF+18432)
#define OFF_H     (OFF_W3BF+73728)      // h bf16 hi/lo [2][8192][1152] ushort
#define OFF_TABLE (OFF_H + 8192*1152)   // table [1024][576] fp32, disjoint from h

__device__ __forceinline__ ushort_t f2bf(float v) {
  uint_t u = __float_as_uint(v);
  return (ushort_t)((u + 0x7FFFu + ((u >> 16) & 1u)) >> 16);
}
__device__ __forceinline__ float bf2f(ushort_t b) {
  return __uint_as_float(((uint_t)b) << 16);
}

// ---------------- merged prep ----------------
#define P2_N (92160 + 294912 + 262144 + 73728 + 18432)
#define PREP_N (WS_WEIGHTS + P2_N)
__global__ void vq_prep_all(const float* __restrict__ conv1_w, const float* __restrict__ conv2_w,
                            const float* __restrict__ conv3_w, const float* __restrict__ enc_fc_w,
                            const float* __restrict__ codebook, const float* __restrict__ dec_fc_w,
                            const float* __restrict__ dct1_w, const float* __restrict__ dct2_w,
                            const float* __restrict__ dct3_w, float* __restrict__ ws) {
  int i0 = blockIdx.x * blockDim.x + threadIdx.x;
  if (i0 >= PREP_N) return;
  if (i0 < WS_WEIGHTS) {
    int i = i0;
    if (i < OFF_BD2F) {
      int tap = i >> 5, co = i & 31;
      ws[i] = conv1_w[co*9 + tap];
    } else if (i < OFF_CC) {
      return;
    } else if (i < OFF_DWT) {
      int k = i - OFF_CC;
      float s = 0.f;
      for (int j = 0; j < 128; ++j) { float v = codebook[k*128+j]; s += v*v; }
      ws[i] = s;
    } else if (i < OFF_D1R) {
      int l = i - OFF_DWT;
      int j = l % 1152, k = l / 1152;
      ws[i] = dec_fc_w[j*128 + k];
    } else if (i < OFF_D3R) {
      return;
    } else {
      int l = i - OFF_D3R;
      int tap = l % 9, ci = l / 9;
      ws[i] = dct3_w[ci*9 + (8 - tap)];
    }
    return;
  }
  int i = i0 - WS_WEIGHTS;
  ushort_t* W2  = (ushort_t*)(ws + OFF_W2BF);
  ushort_t* W3  = (ushort_t*)(ws + OFF_W3BF);
  ushort_t* EW  = (ushort_t*)(ws + OFF_EWT);
  ushort_t* CB  = (ushort_t*)(ws + OFF_CT);
  ushort_t* BD1 = (ushort_t*)(ws + OFF_BD1F);
  ushort_t* BD2 = (ushort_t*)(ws + OFF_BD2F);
  if (i < 18432) {
    int tap = i >> 11, r = i & 2047, co = r >> 5, ch = r & 31;
    float v = conv2_w[(co*32 + ch)*9 + tap];
    ushort_t hb = f2bf(v);
    W2[i] = hb; W2[18432 + i] = f2bf(v - bf2f(hb));
  } else if (i < 92160) {
    int j = i - 18432;
    int tap = j >> 13, r = j & 8191, co = r >> 6, ch = r & 63;
    float v = conv3_w[(co*64 + ch)*9 + tap];
    ushort_t hb = f2bf(v);
    W3[j] = hb; W3[73728 + j] = f2bf(v - bf2f(hb));
  } else if (i < 387072) {
    int r = i - 92160;
    int p = r / 147456; r %= 147456;
    int kk = r & 31, n = (r >> 5) & 127, ks = r >> 12;
    float v = enc_fc_w[n*1152 + ks*32 + kk];
    ushort_t hb = f2bf(v);
    if (p == 0) EW[r] = hb; else EW[147456 + r] = f2bf(v - bf2f(hb));
  } else if (i < 649216) {
    int r = i - 387072;
    int p = r / 131072; r %= 131072;
    int kk = r & 31, cw = (r >> 5) & 1023, ks = r >> 15;
    float v = codebook[cw*128 + ks*32 + kk];
    ushort_t hb = f2bf(v);
    if (p == 0) CB[r] = hb; else CB[131072 + r] = f2bf(v - bf2f(hb));
  } else if (i < 722944) {
    int r = i - 649216;
    int co = r / 1152, k = r - co*1152;
    int tap = k >> 7, ci = k & 127;
    float v = dct1_w[(ci*64 + co)*9 + (8 - tap)];
    ushort_t hb = f2bf(v);
    BD1[r] = hb; BD1[73728 + r] = f2bf(v - bf2f(hb));
  } else {
    int r = i - 722944;
    int co = r / 576, k = r - co*576;
    int tap = k >> 6, ci = k & 63;
    float v = dct2_w[(ci*32 + co)*9 + (8 - tap)];
    ushort_t hb = f2bf(v);
    BD2[r] = hb; BD2[18432 + r] = f2bf(v - bf2f(hb));
  }
}

// ---------------- encoder (round-8 code, measured 412 µs) ----------------
__global__ __launch_bounds__(256, 4) void vq_enc(
    const float* __restrict__ x,
    const float* __restrict__ b1, const float* __restrict__ b2, const float* __restrict__ b3,
    const float* __restrict__ ws, ushort_t* __restrict__ hhi, ushort_t* __restrict__ hlo)
{
  __shared__ ushort_t R0h[7840], R0l[7840];
  __shared__ float XT[624];
  ushort_t* C3h = R0h;
  ushort_t* C3l = R0l;
  const int t = threadIdx.x;
  const int b = blockIdx.x;

  for (int i = t; i < 3920; i += 256) { ((uint_t*)R0h)[i] = 0u; ((uint_t*)R0l)[i] = 0u; }
  const float* xb = x + (size_t)b * 576;
  for (int i = t; i < 624; i += 256) {
    int row = i / 26, col = i - row * 26;
    XT[i] = (col >= 1 && col <= 24) ? xb[row*24 + col - 1] : 0.f;
  }
  __syncthreads();

  // ---- conv1 ----
  {
    int co = t & 31, g = t >> 5, gy = g >> 1, gx = g & 1;
    float w[9];
    #pragma unroll
    for (int k = 0; k < 9; ++k) w[k] = ws[OFF_W1R + k*32 + co];
    float bias = b1[co];
    #pragma unroll
    for (int pr = 0; pr < 3; ++pr) {
      int Y = gy*6 + pr*2;
      float a0[12], a1[12];
      #pragma unroll
      for (int i = 0; i < 12; ++i) { a0[i] = 0.f; a1[i] = 0.f; }
      #pragma unroll
      for (int wy = 0; wy < 4; ++wy) {
        int ry = Y - 1 + wy;
        if (ry < 0 || ry > 23) continue;
        const float2* rp = (const float2*)&XT[ry*26 + gx*12];
        float r[14];
        #pragma unroll
        for (int k = 0; k < 7; ++k) { float2 p = rp[k]; r[2*k] = p.x; r[2*k+1] = p.y; }
        if (wy < 3) {
          #pragma unroll
          for (int xx = 0; xx < 12; ++xx)
            #pragma unroll
            for (int dx = 0; dx < 3; ++dx) a0[xx] += r[xx+dx] * w[wy*3+dx];
        }
        if (wy >= 1) {
          #pragma unroll
          for (int xx = 0; xx < 12; ++xx)
            #pragma unroll
            for (int dx = 0; dx < 3; ++dx) a1[xx] += r[xx+dx] * w[(wy-1)*3+dx];
        }
      }
      #pragma unroll
      for (int pc = 0; pc < 6; ++pc) {
        float m = fmaxf(fmaxf(a0[2*pc], a0[2*pc+1]), fmaxf(a1[2*pc], a1[2*pc+1]));
        float v = m + bias; v = v > 0.f ? v : 0.f;
        int row = gy*3 + pr, colp = gx*6 + pc;
        int addr = ((row+1)*14 + (colp+1))*40 + co;
        ushort_t hb = f2bf(v);
        R0h[addr] = hb;
        R0l[addr] = f2bf(v - bf2f(hb));
      }
    }
  }
  __syncthreads();

  const int lane = t & 63, quad = lane >> 4, col = lane & 15;
  const int wv = t >> 6;

  // ---- conv2 MFMA ----
  {
    const int h = wv & 1, p = wv >> 1;
    const ushort_t* W2 = (const ushort_t*)(ws + OFF_W2BF);
    int baseA[5];
    #pragma unroll
    for (int mi = 0; mi < 5; ++mi) {
      int m = (h*5 + mi)*16 + col; if (m > 143) m = 143;
      int cell = m >> 2, sub = m & 3;
      int opy = cell / 6, opx = cell - opy*6;
      int y = 2*opy + (sub >> 1), xx = 2*opx + (sub & 1);
      baseA[mi] = (y*14 + xx)*40 + quad*8;
    }
    f32x4 acc[5][2];
    #pragma unroll
    for (int mi = 0; mi < 5; ++mi) { acc[mi][0] = (f32x4)0.f; acc[mi][1] = (f32x4)0.f; }
    const int co0 = p*32 + col, co1 = co0 + 16;
    #pragma unroll
    for (int t9 = 0; t9 < 9; ++t9) {
      const int TAPOFF = ((t9/3)*14 + (t9%3))*40;
      int bidx = t9*2048 + quad*8;
      short8 Bh0 = *(const short8*)(W2 + bidx + co0*32);
      short8 Bh1 = *(const short8*)(W2 + bidx + co1*32);
      short8 Bl0 = *(const short8*)(W2 + 18432 + bidx + co0*32);
      short8 Bl1 = *(const short8*)(W2 + 18432 + bidx + co1*32);
      #pragma unroll
      for (int mi = 0; mi < 5; ++mi) {
        int a = baseA[mi] + TAPOFF;
        short8 Ah = *(const short8*)(R0h + a);
        short8 Al = *(const short8*)(R0l + a);
        acc[mi][0] = __builtin_amdgcn_mfma_f32_16x16x32_bf16(Al, Bh0, acc[mi][0], 0, 0, 0);
        acc[mi][0] = __builtin_amdgcn_mfma_f32_16x16x32_bf16(Ah, Bl0, acc[mi][0], 0, 0, 0);
        acc[mi][0] = __builtin_amdgcn_mfma_f32_16x16x32_bf16(Ah, Bh0, acc[mi][0], 0, 0, 0);
        acc[mi][1] = __builtin_amdgcn_mfma_f32_16x16x32_bf16(Al, Bh1, acc[mi][1], 0, 0, 0);
        acc[mi][1] = __builtin_amdgcn_mfma_f32_16x16x32_bf16(Ah, Bl1, acc[mi][1], 0, 0, 0);
        acc[mi][1] = __builtin_amdgcn_mfma_f32_16x16x32_bf16(Ah, Bh1, acc[mi][1], 0, 0, 0);
      }
    }
    __syncthreads();
    for (int i = t; i < 2304; i += 256) { ((uint_t*)C3h)[i] = 0u; ((uint_t*)C3l)[i] = 0u; }
    __syncthreads();
    #pragma unroll
    for (int mi = 0; mi < 5; ++mi) {
      int cell = (h*5 + mi)*4 + quad;
      if (cell < 36) {
        int opy = cell / 6, opx = cell - opy*6;
        int wa = ((opy+1)*8 + (opx+1))*72;
        #pragma unroll
        for (int j = 0; j < 2; ++j) {
          int ch = j ? co1 : co0;
          f32x4 a = acc[mi][j];
          float v = fmaxf(fmaxf(a.x, a.y), fmaxf(a.z, a.w)) + b2[ch];
          v = v > 0.f ? v : 0.f;
          ushort_t hb = f2bf(v);
          C3h[wa + ch] = hb;
          C3l[wa + ch] = f2bf(v - bf2f(hb));
        }
      }
    }
  }
  __syncthreads();

  // ---- conv3 MFMA ----
  {
    const ushort_t* W3 = (const ushort_t*)(ws + OFF_W3BF);
    int baseA[3];
    #pragma unroll
    for (int mt = 0; mt < 3; ++mt) {
      int m = mt*16 + col; if (m > 35) m = 35;
      int cell = m >> 2, sub = m & 3;
      int opy = cell / 3, opx = cell - opy*3;
      int y = 2*opy + (sub >> 1), xx = 2*opx + (sub & 1);
      baseA[mt] = (y*8 + xx)*72 + quad*8;
    }
    f32x4 acc[3][2];
    #pragma unroll
    for (int mt = 0; mt < 3; ++mt) { acc[mt][0] = (f32x4)0.f; acc[mt][1] = (f32x4)0.f; }
    const int co0 = wv*16 + col, co1 = co0 + 64;
    #pragma unroll
    for (int ks = 0; ks < 18; ++ks) {
      const int t9 = ks >> 1, ch0 = (ks & 1)*32;
      const int TAPOFF = ((t9/3)*8 + (t9%3))*72;
      int bidx = t9*8192 + ch0 + quad*8;
      short8 Bh0 = *(const short8*)(W3 + bidx + co0*64);
      short8 Bh1 = *(const short8*)(W3 + bidx + co1*64);
      short8 Bl0 = *(const short8*)(W3 + 73728 + bidx + co0*64);
      short8 Bl1 = *(const short8*)(W3 + 73728 + bidx + co1*64);
      #pragma unroll
      for (int mt = 0; mt < 3; ++mt) {
        int a = baseA[mt] + TAPOFF + ch0;
        short8 Ah = *(const short8*)(C3h + a);
        short8 Al = *(const short8*)(C3l + a);
        acc[mt][0] = __builtin_amdgcn_mfma_f32_16x16x32_bf16(Al, Bh0, acc[mt][0], 0, 0, 0);
        acc[mt][0] = __builtin_amdgcn_mfma_f32_16x16x32_bf16(Ah, Bl0, acc[mt][0], 0, 0, 0);
        acc[mt][0] = __builtin_amdgcn_mfma_f32_16x16x32_bf16(Ah, Bh0, acc[mt][0], 0, 0, 0);
        acc[mt][1] = __builtin_amdgcn_mfma_f32_16x16x32_bf16(Al, Bh1, acc[mt][1], 0, 0, 0);
        acc[mt][1] = __builtin_amdgcn_mfma_f32_16x16x32_bf16(Ah, Bl1, acc[mt][1], 0, 0, 0);
        acc[mt][1] = __builtin_amdgcn_mfma_f32_16x16x32_bf16(Ah, Bh1, acc[mt][1], 0, 0, 0);
      }
    }
    ushort_t* hb_ = hhi + (size_t)b * 1152;
    ushort_t* lb_ = hlo + (size_t)b * 1152;
    #pragma unroll
    for (int mt = 0; mt < 3; ++mt) {
      int cell = mt*4 + quad;
      if (cell < 9) {
        #pragma unroll
        for (int j = 0; j < 2; ++j) {
          int ch = j ? co1 : co0;
          f32x4 a = acc[mt][j];
          float v = fmaxf(fmaxf(a.x, a.y), fmaxf(a.z, a.w)) + b3[ch];
          v = v > 0.f ? v : 0.f;
          ushort_t hb2 = f2bf(v);
          hb_[ch*9 + cell] = hb2;
          lb_[ch*9 + cell] = f2bf(v - bf2f(hb2));
        }
      }
    }
  }
}

// ---------------- decode table via MFMA D1/D2 (round-8 code): 1 codeword/block ------------
__global__ __launch_bounds__(256, 4) void vq_dec_table(
    const float* __restrict__ codebook, const float* __restrict__ decb,
    const float* __restrict__ d1b, const float* __restrict__ d2b, const float* __restrict__ d3b,
    const float* __restrict__ ws, float* __restrict__ table)
{
  __shared__ float POOL[8008];
  __shared__ float PS[1536];
  __shared__ float ZQ[128];
  ushort_t* FAh = (ushort_t*)POOL;
  ushort_t* FAl = FAh + 3400;
  ushort_t* GAh = (ushort_t*)(POOL + 3400);
  ushort_t* GAl = GAh + 4608;
  float* R2 = POOL;

  const int t = threadIdx.x;
  const int cw = blockIdx.x;
  const int lane = t & 63, wv = t >> 6;
  const int col = lane & 15, quad = lane >> 4;

  for (int i = t; i < 8008; i += 256) POOL[i] = 0.f;
  if (t < 128) ZQ[t] = codebook[(size_t)cw*128 + t];
  __syncthreads();

  #pragma unroll
  for (int p = 0; p < 5; ++p) {
    int j = t + p*256;
    if (j < 1152) {
      float a0 = decb[j];
      const float* wb = ws + OFF_DWT + j;
      #pragma unroll 4
      for (int k = 0; k < 128; ++k) a0 += wb[k*1152] * ZQ[k];
      int ci = j / 9, rem = j - ci*9;
      int pix = ((rem/3)+1)*5 + (rem%3) + 1;
      ushort_t hb = f2bf(a0);
      FAh[pix*136 + ci] = hb;
      FAl[pix*136 + ci] = f2bf(a0 - bf2f(hb));
    }
  }
  __syncthreads();

  const ushort_t* BD1 = (const ushort_t*)(ws + OFF_BD1F);
  f32x4 acc1 = (f32x4)0.f;
  {
    const int m9 = col < 9 ? col : 8;
    const int oy = m9/3, ox = m9 - oy*3;
    const int co = wv*16 + col;
    #pragma unroll 4
    for (int ks = 0; ks < 36; ++ks) {
      int kb = ks*32 + quad*8;
      int tap = kb >> 7, ci0 = kb & 127;
      int pix = (oy + tap/3)*5 + ox + tap%3;
      short8 Ah = *(const short8*)(FAh + pix*136 + ci0);
      short8 Al = *(const short8*)(FAl + pix*136 + ci0);
      const ushort_t* bp = BD1 + co*1152 + kb;
      short8 Bh = *(const short8*)bp;
      short8 Bl = *(const short8*)(bp + 73728);
      acc1 = __builtin_amdgcn_mfma_f32_16x16x32_bf16(Al, Bh, acc1, 0, 0, 0);
      acc1 = __builtin_amdgcn_mfma_f32_16x16x32_bf16(Ah, Bl, acc1, 0, 0, 0);
      acc1 = __builtin_amdgcn_mfma_f32_16x16x32_bf16(Ah, Bh, acc1, 0, 0, 0);
    }
  }
  {
    const int co = wv*16 + col;
    float bias = d1b[co];
    #pragma unroll
    for (int r = 0; r < 4; ++r) {
      int m = quad*4 + r;
      if (m < 9) {
        int oy = m/3, ox = m - oy*3;
        float v = acc1[r] + bias; v = v > 0.f ? v : 0.f;
        ushort_t hb = f2bf(v), lb = f2bf(v - bf2f(hb));
        int rbase = (2*oy+1)*8 + (2*ox+1);
        GAh[(rbase  )*72 + co] = hb; GAh[(rbase+1)*72 + co] = hb;
        GAh[(rbase+8)*72 + co] = hb; GAh[(rbase+9)*72 + co] = hb;
        GAl[(rbase  )*72 + co] = lb; GAl[(rbase+1)*72 + co] = lb;
        GAl[(rbase+8)*72 + co] = lb; GAl[(rbase+9)*72 + co] = lb;
      }
    }
  }
  __syncthreads();

  const ushort_t* BD2 = (const ushort_t*)(ws + OFF_BD2F);
  f32x4 acc2[3];
  acc2[0] = (f32x4)0.f; acc2[1] = (f32x4)0.f; acc2[2] = (f32x4)0.f;
  const int h = wv >> 1, js = (wv & 1)*3;
  for (int ks = h*9; ks < h*9 + 9; ++ks) {
    int kb = ks*32 + quad*8;
    int tap = kb >> 6, ci0 = kb & 63;
    int ty = tap/3, tx = tap - ty*3;
    #pragma unroll
    for (int jj = 0; jj < 3; ++jj) {
      int job = js + jj;
      int mt = job >> 1, nt = job & 1;
      int m = mt*16 + col; if (m > 35) m = 35;
      int oy = m/6, ox = m - oy*6;
      int pix = (oy+ty)*8 + ox+tx;
      short8 Ah = *(const short8*)(GAh + pix*72 + ci0);
      short8 Al = *(const short8*)(GAl + pix*72 + ci0);
      int co = nt*16 + col;
      const ushort_t* bp = BD2 + co*576 + kb;
      short8 Bh = *(const short8*)bp;
      short8 Bl = *(const short8*)(bp + 18432);
      acc2[jj] = __builtin_amdgcn_mfma_f32_16x16x32_bf16(Al, Bh, acc2[jj], 0, 0, 0);
      acc2[jj] = __builtin_amdgcn_mfma_f32_16x16x32_bf16(Ah, Bl, acc2[jj], 0, 0, 0);
      acc2[jj] = __builtin_amdgcn_mfma_f32_16x16x32_bf16(Ah, Bh, acc2[jj], 0, 0, 0);
    }
  }
  __syncthreads();
  if (h == 1) {
    #pragma unroll
    for (int jj = 0; jj < 3; ++jj) {
      int job = js + jj;
      #pragma unroll
      for (int r = 0; r < 4; ++r) PS[(job*64 + lane)*4 + r] = acc2[jj][r];
    }
  }
  for (int i = t; i < 6468; i += 256) R2[i] = 0.f;
  __syncthreads();
  if (h == 0) {
    #pragma unroll
    for (int jj = 0; jj < 3; ++jj) {
      int job = js + jj;
      int mt = job >> 1, nt = job & 1;
      int co = nt*16 + col;
      float bias = d2b[co];
      #pragma unroll
      for (int r = 0; r < 4; ++r) {
        float v = acc2[jj][r] + PS[(job*64 + lane)*4 + r];
        int m = mt*16 + quad*4 + r;
        if (m < 36) {
          int oy = m/6, ox = m - oy*6;
          v += bias; v = v > 0.f ? v : 0.f;
          int rbase = (2*oy+1)*14 + (2*ox+1);
          R2[(rbase   )*33 + co] = v; R2[(rbase+ 1)*33 + co] = v;
          R2[(rbase+14)*33 + co] = v; R2[(rbase+15)*33 + co] = v;
        }
      }
    }
  }
  __syncthreads();

  if (t < 144) {
    int yy = t / 12, xx = t - yy*12;
    const float* w3 = ws + OFF_D3R;
    float acc = d3b[0];
    #pragma unroll
    for (int dy = 0; dy < 3; ++dy)
      #pragma unroll
      for (int dx = 0; dx < 3; ++dx) {
        const float* rp = &R2[((yy+dy)*14 + xx+dx)*33];
        const float* wp = w3 + dy*3 + dx;
        #pragma unroll 8
        for (int ci = 0; ci < 32; ++ci) acc += rp[ci] * wp[ci*9];
      }
    float v = acc > 0.f ? acc : 0.f;
    float* ob = table + (size_t)cw * 576;
    int o0 = (2*yy)*24 + 2*xx;
    ob[o0] = v; ob[o0+1] = v; ob[o0+24] = v; ob[o0+25] = v;
  }
}

// ---------------- fused enc_fc + argmin + scatter: 32 samples/block (round-9, verified) -----
__global__ __launch_bounds__(256, 2) void vq_fc_argmin_scatter(
    const float* __restrict__ efb, const float* __restrict__ ws,
    const ushort_t* __restrict__ hhi, const ushort_t* __restrict__ hlo,
    const float* __restrict__ table, float* __restrict__ out)
{
  __shared__ float ZL[32*132];
  __shared__ float WVs[128];
  __shared__ int   WIs[128];
  __shared__ int   IDX[32];
  const int t = threadIdx.x;
  const int sb = blockIdx.x * 32;
  const int lane = t & 63, wv = t >> 6;
  const int col = lane & 15, quad = lane >> 4;

  const ushort_t* EW  = (const ushort_t*)(ws + OFF_EWT);
  const ushort_t* CBB = (const ushort_t*)(ws + OFF_CT);

  f32x4 acc[2][2];
  acc[0][0] = (f32x4)0.f; acc[0][1] = (f32x4)0.f;
  acc[1][0] = (f32x4)0.f; acc[1][1] = (f32x4)0.f;
  const size_t hrow0 = (size_t)(sb + col) * 1152 + quad*8;
  const size_t hrow1 = (size_t)(sb + 16 + col) * 1152 + quad*8;
  const int n0 = wv*32 + col, n1 = n0 + 16;
  #pragma unroll 2
  for (int ks = 0; ks < 36; ++ks) {
    short8 Ah0 = *(const short8*)(hhi + hrow0 + ks*32);
    short8 Al0 = *(const short8*)(hlo + hrow0 + ks*32);
    short8 Ah1 = *(const short8*)(hhi + hrow1 + ks*32);
    short8 Al1 = *(const short8*)(hlo + hrow1 + ks*32);
    const ushort_t* bp0 = EW + (ks*128 + n0)*32 + quad*8;
    const ushort_t* bp1 = EW + (ks*128 + n1)*32 + quad*8;
    short8 Bh0 = *(const short8*)(bp0);
    short8 Bl0 = *(const short8*)(bp0 + 147456);
    short8 Bh1 = *(const short8*)(bp1);
    short8 Bl1 = *(const short8*)(bp1 + 147456);
    acc[0][0] = __builtin_amdgcn_mfma_f32_16x16x32_bf16(Al0, Bh0, acc[0][0], 0, 0, 0);
    acc[0][0] = __builtin_amdgcn_mfma_f32_16x16x32_bf16(Ah0, Bl0, acc[0][0], 0, 0, 0);
    acc[0][0] = __builtin_amdgcn_mfma_f32_16x16x32_bf16(Ah0, Bh0, acc[0][0], 0, 0, 0);
    acc[0][1] = __builtin_amdgcn_mfma_f32_16x16x32_bf16(Al0, Bh1, acc[0][1], 0, 0, 0);
    acc[0][1] = __builtin_amdgcn_mfma_f32_16x16x32_bf16(Ah0, Bl1, acc[0][1], 0, 0, 0);
    acc[0][1] = __builtin_amdgcn_mfma_f32_16x16x32_bf16(Ah0, Bh1, acc[0][1], 0, 0, 0);
    acc[1][0] = __builtin_amdgcn_mfma_f32_16x16x32_bf16(Al1, Bh0, acc[1][0], 0, 0, 0);
    acc[1][0] = __builtin_amdgcn_mfma_f32_16x16x32_bf16(Ah1, Bl0, acc[1][0], 0, 0, 0);
    acc[1][0] = __builtin_amdgcn_mfma_f32_16x16x32_bf16(Ah1, Bh0, acc[1][0], 0, 0, 0);
    acc[1][1] = __builtin_amdgcn_mfma_f32_16x16x32_bf16(Al1, Bh1, acc[1][1], 0, 0, 0);
    acc[1][1] = __builtin_amdgcn_mfma_f32_16x16x32_bf16(Ah1, Bl1, acc[1][1], 0, 0, 0);
    acc[1][1] = __builtin_amdgcn_mfma_f32_16x16x32_bf16(Ah1, Bh1, acc[1][1], 0, 0, 0);
  }
  {
    float bs0 = efb[n0], bs1 = efb[n1];
    #pragma unroll
    for (int m2 = 0; m2 < 2; ++m2) {
      #pragma unroll
      for (int r = 0; r < 4; ++r) {
        int m = m2*16 + quad*4 + r;
        ZL[m*132 + n0] = acc[m2][0][r] + bs0;
        ZL[m*132 + n1] = acc[m2][1][r] + bs1;
      }
    }
  }
  __syncthreads();

  short8 zAh[2][4], zAl[2][4];
  #pragma unroll
  for (int m2 = 0; m2 < 2; ++m2) {
    #pragma unroll
    for (int ks = 0; ks < 4; ++ks) {
      const float* zp = &ZL[(m2*16 + col)*132 + ks*32 + quad*8];
      float4 z0 = *(const float4*)zp;
      float4 z1 = *(const float4*)(zp + 4);
      float zv[8] = {z0.x, z0.y, z0.z, z0.w, z1.x, z1.y, z1.z, z1.w};
      ushort_t ph[8], pl[8];
      #pragma unroll
      for (int e = 0; e < 8; ++e) {
        ushort_t hb = f2bf(zv[e]);
        ph[e] = hb; pl[e] = f2bf(zv[e] - bf2f(hb));
      }
      zAh[m2][ks] = *(const short8*)ph;
      zAl[m2][ks] = *(const short8*)pl;
    }
  }

  float bestv[2][4]; int besti[2][4];
  #pragma unroll
  for (int m2 = 0; m2 < 2; ++m2)
    #pragma unroll
    for (int r = 0; r < 4; ++r) { bestv[m2][r] = 3.4e38f; besti[m2][r] = 0; }
  for (int c4 = 0; c4 < 4; ++c4) {
    f32x4 dacc[2][4];
    #pragma unroll
    for (int m2 = 0; m2 < 2; ++m2)
      #pragma unroll
      for (int nn = 0; nn < 4; ++nn) dacc[m2][nn] = (f32x4)0.f;
    #pragma unroll
    for (int ks = 0; ks < 4; ++ks) {
      #pragma unroll
      for (int nn = 0; nn < 4; ++nn) {
        int cw = (wv*16 + c4*4 + nn)*16 + col;
        const ushort_t* bp = CBB + (size_t)(ks*1024 + cw)*32 + quad*8;
        short8 Bh = *(const short8*)bp;
        short8 Bl = *(const short8*)(bp + 131072);
        #pragma unroll
        for (int m2 = 0; m2 < 2; ++m2) {
          dacc[m2][nn] = __builtin_amdgcn_mfma_f32_16x16x32_bf16(zAl[m2][ks], Bh, dacc[m2][nn], 0, 0, 0);
          dacc[m2][nn] = __builtin_amdgcn_mfma_f32_16x16x32_bf16(zAh[m2][ks], Bl, dacc[m2][nn], 0, 0, 0);
          dacc[m2][nn] = __builtin_amdgcn_mfma_f32_16x16x32_bf16(zAh[m2][ks], Bh, dacc[m2][nn], 0, 0, 0);
        }
      }
    }
    #pragma unroll
    for (int nn = 0; nn < 4; ++nn) {
      int cw = (wv*16 + c4*4 + nn)*16 + col;
      float ccv = ws[OFF_CC + cw];
      #pragma unroll
      for (int m2 = 0; m2 < 2; ++m2)
        #pragma unroll
        for (int r = 0; r < 4; ++r) {
          float dist = ccv - 2.f*dacc[m2][nn][r];
          if (dist < bestv[m2][r]) { bestv[m2][r] = dist; besti[m2][r] = cw; }
        }
    }
  }

  #pragma unroll
  for (int m2 = 0; m2 < 2; ++m2)
    #pragma unroll
    for (int r = 0; r < 4; ++r) {
      float v = bestv[m2][r]; int ii = besti[m2][r];
      #pragma unroll
      for (int off = 8; off >= 1; off >>= 1) {
        float v2 = __shfl_xor(v, off); int i2 = __shfl_xor(ii, off);
        if (v2 < v || (v2 == v && i2 < ii)) { v = v2; ii = i2; }
      }
      if (col == 0) {
        int m = m2*16 + quad*4 + r;
        WVs[wv*32 + m] = v; WIs[wv*32 + m] = ii;
      }
    }
  __syncthreads();
  if (t < 32) {
    float v = WVs[t]; int ii = WIs[t];
    #pragma unroll
    for (int w2 = 1; w2 < 4; ++w2) {
      float v2 = WVs[w2*32 + t]; int i2 = WIs[w2*32 + t];
      if (v2 < v || (v2 == v && i2 < ii)) { v = v2; ii = i2; }
    }
    IDX[t] = ii;
  }
  __syncthreads();

  const float4* tb4 = (const float4*)table;
  float4* out4 = (float4*)(out + (size_t)sb * 576);
  for (int i = t; i < 32*144; i += 256) {
    int s = i / 144, r = i - s*144;
    out4[s*144 + r] = tb4[(size_t)IDX[s]*144 + r];
  }
}

extern "C" void kernel_launch(void* const* d_in, const int* in_sizes, int n_in,
                              void* d_out, int out_size, void* d_ws, size_t ws_size,
                              hipStream_t stream) {
  const float* x   = (const float*)d_in[0];
  const float* c1w = (const float*)d_in[1];
  const float* c1b = (const float*)d_in[2];
  const float* c2w = (const float*)d_in[3];
  const float* c2b = (const float*)d_in[4];
  const float* c3w = (const float*)d_in[5];
  const float* c3b = (const float*)d_in[6];
  const float* efw = (const float*)d_in[7];
  const float* efb = (const float*)d_in[8];
  const float* cb  = (const float*)d_in[9];
  const float* dfw = (const float*)d_in[10];
  const float* dfb = (const float*)d_in[11];
  const float* dw1 = (const float*)d_in[12];
  const float* db1 = (const float*)d_in[13];
  const float* dw2 = (const float*)d_in[14];
  const float* db2 = (const float*)d_in[15];
  const float* dw3 = (const float*)d_in[16];
  const float* db3 = (const float*)d_in[17];
  float* ws = (float*)d_ws;
  ushort_t* hhi  = (ushort_t*)(ws + OFF_H);
  ushort_t* hlo  = hhi + (size_t)8192*1152;
  float* table = ws + OFF_TABLE;
  float* outp = (float*)d_out;
  int B = in_sizes[0] / 576;

  vq_prep_all<<<(PREP_N + 255) / 256, 256, 0, stream>>>(c1w, c2w, c3w, efw, cb, dfw, dw1, dw2, dw3, ws);
  vq_enc<<<B, 256, 0, stream>>>(x, c1b, c2b, c3b, ws, hhi, hlo);
  vq_dec_table<<<1024, 256, 0, stream>>>(cb, dfb, db1, db2, db3, ws, table);
  vq_fc_argmin_scatter<<<B/32, 256, 0, stream>>>(efb, ws, hhi, hlo, table, outp);
}